// Round 12
// baseline (269.399 us; speedup 1.0000x reference)
//
#include <hip/hip_runtime.h>

#define TT   512
#define HH   50
#define MB   8            // batch rows per block
#define NW   7            // waves per block
#define NTHR (NW * 64)    // 448 threads
#define BUFH 2560         // f16 per parity buffer: 5 strips x 512

typedef _Float16 f16x8 __attribute__((ext_vector_type(8)));
typedef float    f32x4 __attribute__((ext_vector_type(4)));

#define L2E 1.4426950408889634f

__device__ __forceinline__ float rcp_f(float v) { return __builtin_amdgcn_rcpf(v); }
__device__ __forceinline__ float ex2_f(float v) { return __builtin_amdgcn_exp2f(v); }

// 7 waves, grid 256. Wave w owns gate-tiles 2w,2w+1 (units 8w..8w+7, A-rows
// interleaved i,f,g,o per unit). Lane (q=l>>4, n=l&15) runs TWO chains:
// chain0 = (unit 8w+q, layer n>=8, batch n&7), chain1 = (unit 8w+4+q, same).
// B operand (shared by both tiles, read ONCE): K=160 block-diagonal
// [h0 cols0-7 | h0copy cols8-15 | h1 cols8-15 | 0]; A = [W_hh0|W_ih1|W_hh1|0]
// stacked along K, pre-scaled by -log2e (i,f,o) / +2log2e (g).
// Bias + x*W_ih0 ride in the MFMA C operand. One barrier per step; layer 1
// pipelined one step behind layer 0. 2-tile concentration halves the LDS
// broadcast (35 vs 65 KB/CU-step) and gives 2-way ILP on MFMA + trans chains.
__global__ __launch_bounds__(NTHR, 1)
void lstm2_kernel(const float* __restrict__ x,
                  const float* __restrict__ W_ih0, const float* __restrict__ W_hh0,
                  const float* __restrict__ b_ih0, const float* __restrict__ b_hh0,
                  const float* __restrict__ W_ih1, const float* __restrict__ W_hh1,
                  const float* __restrict__ b_ih1, const float* __restrict__ b_hh1,
                  const float* __restrict__ W_fc,  const float* __restrict__ b_fc,
                  float* __restrict__ out)
{
    // B layout per parity buf: f16 offset(row r, col c) =
    //   (r>>5)*512 + ((r>>3)&3)*128 + c*8 + (r&7)
    // Lane l's strip-ki read = buf + ki*512 + 8*l (16B, lane-linear, conflict-free).
    __shared__ __align__(16) _Float16 shh[2][BUFH];          // 10 KiB
    __shared__ float sh_x[MB][TT + 4];
    __shared__ float shf[MB][56];
    __shared__ float sh_wfc[HH];

    const int tid = threadIdx.x;
    const int w   = tid >> 6;
    const int l   = tid & 63;
    const int q   = l >> 4;
    const int n   = l & 15;
    const int b0  = blockIdx.x * MB;

    for (int i = tid; i < 2 * BUFH; i += NTHR) (&shh[0][0])[i] = (_Float16)0.0f;
    for (int i = tid; i < MB * TT; i += NTHR)
        sh_x[i >> 9][i & (TT - 1)] = x[(size_t)b0 * TT + i];
    for (int i = tid; i < HH; i += NTHR) sh_wfc[i] = W_fc[i];

    // ---- A fragments, 2 tiles, K=160 concat [W_hh0|W_ih1|W_hh1|0], pre-scaled.
    // Tile t: A-row r=n -> unit 8w+4t+(n>>2), gate n&3, row grow=(n&3)*HH+ur.
    // k-map: k = ki*32 + q*8 + e (same bijection as B layout -> sums correct).
    const float srow = ((n & 3) == 2) ? (2.0f * L2E) : (-L2E);
    f16x8 wf0[5], wf1[5];

#define LOADW(WF, TOFF)                                                           \
    {                                                                             \
        int ur   = 8 * w + (TOFF) + (n >> 2);                                     \
        bool rok = (ur < HH);                                                     \
        int grow = (n & 3) * HH + (rok ? ur : 0);                                 \
        _Pragma("unroll")                                                         \
        for (int ki = 0; ki < 5; ++ki) {                                          \
            _Pragma("unroll")                                                     \
            for (int e = 0; e < 8; ++e) {                                         \
                int k = ki * 32 + q * 8 + e;                                      \
                float v = 0.0f;                                                   \
                if (rok) {                                                        \
                    if      (k < HH)      v = W_hh0[grow * HH + k];               \
                    else if (k < 2 * HH)  v = W_ih1[grow * HH + (k - HH)];        \
                    else if (k < 3 * HH)  v = W_hh1[grow * HH + (k - 2 * HH)];    \
                }                                                                 \
                WF[ki][e] = (_Float16)(srow * v);                                 \
            }                                                                     \
        }                                                                         \
    }
    LOADW(wf0, 0)
    LOADW(wf1, 4)
#undef LOADW

    // ---- chain identities ----
    const bool isL1 = (n >= 8);
    const int  cb   = n & 7;
    const int  u0   = 8 * w + q,      u1 = u0 + 4;
    const bool wr0  = (u0 < HH),      wr1 = (u1 < HH);
    const int  uc0  = wr0 ? u0 : 0;
    const int  uc1  = wr1 ? u1 : 0;

    float bz0[4], wz0[4], bz1[4], wz1[4];
    #pragma unroll
    for (int e = 0; e < 4; ++e) {
        float sc = (e == 2) ? (2.0f * L2E) : (-L2E);
        int g0 = e * HH + uc0, g1 = e * HH + uc1;
        bz0[e] = sc * (isL1 ? (b_ih1[g0] + b_hh1[g0]) : (b_ih0[g0] + b_hh0[g0]));
        bz1[e] = sc * (isL1 ? (b_ih1[g1] + b_hh1[g1]) : (b_ih0[g1] + b_hh0[g1]));
        wz0[e] = isL1 ? 0.0f : (sc * W_ih0[g0]);
        wz1[e] = isL1 ? 0.0f : (sc * W_ih0[g1]);
    }

    // ---- LDS pointers ----
    auto offrc = [](int r, int c) {
        return (r >> 5) * 512 + ((r >> 3) & 3) * 128 + c * 8 + (r & 7);
    };
    const _Float16* rb = &shh[0][8 * l];               // + P*BUFH + ki*512
    const int oa0 = isL1 ? offrc(100 + uc0, cb + 8) : offrc(uc0, cb);
    const int ob0 = offrc(50 + uc0, cb + 8);
    const int oa1 = isL1 ? offrc(100 + uc1, cb + 8) : offrc(uc1, cb);
    const int ob1 = offrc(50 + uc1, cb + 8);

    const float* xq = &sh_x[cb][0];
    float cst0 = 0.0f, cst1 = 0.0f;

    __syncthreads();

#define MFMA(A, B, C) __builtin_amdgcn_mfma_f32_16x16x32_f16((A), (B), (C), 0, 0, 0)

#define CHAIN(ACC, CST, T0, HV)                                                   \
    {                                                                             \
        float eI = ex2_f(ACC[0]), eF = ex2_f(ACC[1]);                             \
        float tG = ex2_f(ACC[2]), eO = ex2_f(ACC[3]);                             \
        float dI = 1.0f + eI, dF = 1.0f + eF, dO = 1.0f + eO;                     \
        float IG = (tG - 1.0f) * rcp_f(dI * (tG + 1.0f));                         \
        float cn = __builtin_fmaf(rcp_f(dF), CST, IG);                            \
        CST = ((T0) && isL1) ? 0.0f : cn;                                         \
        float cc = __builtin_amdgcn_fmed3f(CST, -16.0f, 16.0f);                   \
        float tc = ex2_f(cc * (2.0f * L2E));                                      \
        HV = (tc - 1.0f) * rcp_f(dO * (tc + 1.0f));                               \
    }

#define STEP(P, T0, XI)                                                           \
    {                                                                             \
        float xi = (XI);                                                          \
        f32x4 cin0, cin1;                                                         \
        cin0[0] = __builtin_fmaf(xi, wz0[0], bz0[0]);                             \
        cin0[1] = __builtin_fmaf(xi, wz0[1], bz0[1]);                             \
        cin0[2] = __builtin_fmaf(xi, wz0[2], bz0[2]);                             \
        cin0[3] = __builtin_fmaf(xi, wz0[3], bz0[3]);                             \
        cin1[0] = __builtin_fmaf(xi, wz1[0], bz1[0]);                             \
        cin1[1] = __builtin_fmaf(xi, wz1[1], bz1[1]);                             \
        cin1[2] = __builtin_fmaf(xi, wz1[2], bz1[2]);                             \
        cin1[3] = __builtin_fmaf(xi, wz1[3], bz1[3]);                             \
        f16x8 b0 = *(const f16x8*)(rb + (P) * BUFH);                              \
        f16x8 b1 = *(const f16x8*)(rb + (P) * BUFH + 512);                        \
        f16x8 b2 = *(const f16x8*)(rb + (P) * BUFH + 1024);                       \
        f16x8 b3 = *(const f16x8*)(rb + (P) * BUFH + 1536);                       \
        f16x8 b4 = *(const f16x8*)(rb + (P) * BUFH + 2048);                       \
        f32x4 a0 = MFMA(wf0[0], b0, cin0);                                        \
        f32x4 a1 = MFMA(wf1[0], b0, cin1);                                        \
        a0 = MFMA(wf0[1], b1, a0);                                                \
        a1 = MFMA(wf1[1], b1, a1);                                                \
        a0 = MFMA(wf0[2], b2, a0);                                                \
        a1 = MFMA(wf1[2], b2, a1);                                                \
        a0 = MFMA(wf0[3], b3, a0);                                                \
        a1 = MFMA(wf1[3], b3, a1);                                                \
        a0 = MFMA(wf0[4], b4, a0);                                                \
        a1 = MFMA(wf1[4], b4, a1);                                                \
        float hv0, hv1;                                                           \
        CHAIN(a0, cst0, T0, hv0)                                                  \
        CHAIN(a1, cst1, T0, hv1)                                                  \
        if (!((T0) && isL1)) {                                                    \
            _Float16* wbuf = &shh[(P) ^ 1][0];                                    \
            if (wr0) {                                                            \
                _Float16 h16 = (_Float16)hv0;                                     \
                wbuf[oa0] = h16;                                                  \
                if (!isL1) wbuf[ob0] = h16;                                       \
            }                                                                     \
            if (wr1) {                                                            \
                _Float16 h16 = (_Float16)hv1;                                     \
                wbuf[oa1] = h16;                                                  \
                if (!isL1) wbuf[ob1] = h16;                                       \
            }                                                                     \
        }                                                                         \
        __syncthreads();                                                          \
    }

    // t=0 (P=0): L1 chains suppressed (h1(-1) stays 0)
    STEP(0, 1, xq[0])
    // t=1..510: 255 (odd,even) pairs
    for (int k2 = 0; k2 < 255; ++k2) {
        STEP(1, 0, xq[1])
        STEP(0, 0, xq[2])
        xq += 2;
    }
    // t=511 (P=1): writes h0(511), h1(510) into buf 0
    STEP(1, 0, xq[1])
#undef STEP

    // ---- tail: h1(511) from buf 0 (h0(511) rows 0-99, h1(510) rows 100-149) ----
    {
        f32x4 cin0 = {bz0[0], bz0[1], bz0[2], bz0[3]};
        f32x4 cin1 = {bz1[0], bz1[1], bz1[2], bz1[3]};
        f16x8 b0 = *(const f16x8*)(rb);
        f16x8 b1 = *(const f16x8*)(rb + 512);
        f16x8 b2 = *(const f16x8*)(rb + 1024);
        f16x8 b3 = *(const f16x8*)(rb + 1536);
        f16x8 b4 = *(const f16x8*)(rb + 2048);
        f32x4 a0 = MFMA(wf0[0], b0, cin0);
        f32x4 a1 = MFMA(wf1[0], b0, cin1);
        a0 = MFMA(wf0[1], b1, a0);
        a1 = MFMA(wf1[1], b1, a1);
        a0 = MFMA(wf0[2], b2, a0);
        a1 = MFMA(wf1[2], b2, a1);
        a0 = MFMA(wf0[3], b3, a0);
        a1 = MFMA(wf1[3], b3, a1);
        a0 = MFMA(wf0[4], b4, a0);
        a1 = MFMA(wf1[4], b4, a1);
        if (isL1) {
            float hv0, hv1;
            CHAIN(a0, cst0, 0, hv0)
            CHAIN(a1, cst1, 0, hv1)
            if (wr0) shf[cb][uc0] = hv0;
            if (wr1) shf[cb][uc1] = hv1;
        }
    }
    __syncthreads();

    if (tid < MB) {
        float s = b_fc[0];
        for (int j = 0; j < HH; ++j) s += shf[tid][j] * sh_wfc[j];
        out[b0 + tid] = s;
    }
#undef CHAIN
#undef MFMA
}

extern "C" void kernel_launch(void* const* d_in, const int* in_sizes, int n_in,
                              void* d_out, int out_size, void* d_ws, size_t ws_size,
                              hipStream_t stream) {
    const float* xin   = (const float*)d_in[0];
    const float* W_ih0 = (const float*)d_in[1];
    const float* W_hh0 = (const float*)d_in[2];
    const float* b_ih0 = (const float*)d_in[3];
    const float* b_hh0 = (const float*)d_in[4];
    const float* W_ih1 = (const float*)d_in[5];
    const float* W_hh1 = (const float*)d_in[6];
    const float* b_ih1 = (const float*)d_in[7];
    const float* b_hh1 = (const float*)d_in[8];
    const float* W_fc  = (const float*)d_in[9];
    const float* b_fc  = (const float*)d_in[10];
    float* out = (float*)d_out;

    lstm2_kernel<<<dim3(2048 / MB), dim3(NTHR), 0, stream>>>(
        xin, W_ih0, W_hh0, b_ih0, b_hh0, W_ih1, W_hh1, b_ih1, b_hh1, W_fc, b_fc, out);
}

// Round 13
// 260.811 us; speedup vs baseline: 1.0329x; 1.0329x over previous
//
#include <hip/hip_runtime.h>

#define TT   512
#define HH   50
#define MB   8            // batch rows per block
#define NW   13           // waves per block
#define NTHR (NW * 64)    // 832 threads
#define BUFH 2560         // f16 per parity buffer: 5 strips x 512

typedef _Float16 f16x8 __attribute__((ext_vector_type(8)));
typedef float    f32x4 __attribute__((ext_vector_type(4)));

#define L2E 1.4426950408889634f

__device__ __forceinline__ float rcp_f(float v) { return __builtin_amdgcn_rcpf(v); }
__device__ __forceinline__ float ex2_f(float v) { return __builtin_amdgcn_exp2f(v); }

// R10 structure (241 us) + ZERO-BROADCAST READS.
// 13 waves, grid 256. Wave w owns gate-tile w. Lane (q=l>>4, n=l&15):
// acc[e] = gate e of unit u=4w+q, col n. B operand K=160 block-diagonal:
// rows 0-49 h0 (cols 0-7), rows 50-99 h0copy (cols 8-15), rows 100-149 h1
// (cols 8-15), rest zeros. A = [W_hh0|W_ih1|W_hh1|0] stacked along K,
// pre-scaled by -log2e (i,f,o) / +2log2e (g); bias + x*W_ih0 in MFMA C.
// NEW: lanes whose 16B B-fragment is structurally all-zero read a SHARED
// 16B zero block (same-address broadcast ~free) instead of distinct zero
// addresses -> LDS bytes per wave-step 5120 -> ~2640, halving the per-CU
// LDS-pipe serialization that dominates the step time.
// One barrier per step; layer 1 pipelined one step behind layer 0.
__global__ __launch_bounds__(NTHR, 1)
void lstm2_kernel(const float* __restrict__ x,
                  const float* __restrict__ W_ih0, const float* __restrict__ W_hh0,
                  const float* __restrict__ b_ih0, const float* __restrict__ b_hh0,
                  const float* __restrict__ W_ih1, const float* __restrict__ W_hh1,
                  const float* __restrict__ b_ih1, const float* __restrict__ b_hh1,
                  const float* __restrict__ W_fc,  const float* __restrict__ b_fc,
                  float* __restrict__ out)
{
    // B layout per parity buf: f16 offset(row r, col c) =
    //   (r>>5)*512 + ((r>>3)&3)*128 + c*8 + (r&7)
    __shared__ __align__(16) _Float16 shh[2][BUFH];          // 10 KiB
    __shared__ __align__(16) _Float16 zblk[8];               // shared zero frag
    __shared__ float sh_x[MB][TT + 4];
    __shared__ float shf[MB][52];
    __shared__ float sh_wfc[HH];

    const int tid = threadIdx.x;
    const int w   = tid >> 6;
    const int l   = tid & 63;
    const int q   = l >> 4;
    const int n   = l & 15;
    const int b0  = blockIdx.x * MB;

    for (int i = tid; i < 2 * BUFH; i += NTHR) (&shh[0][0])[i] = (_Float16)0.0f;
    if (tid < 8) zblk[tid] = (_Float16)0.0f;
    for (int i = tid; i < MB * TT; i += NTHR)
        sh_x[i >> 9][i & (TT - 1)] = x[(size_t)b0 * TT + i];
    for (int i = tid; i < HH; i += NTHR) sh_wfc[i] = W_fc[i];

    // ---- A fragments: K=160 concat [W_hh0 | W_ih1 | W_hh1 | 0], pre-scaled.
    // A-row r=n -> unit 4w+(n>>2), gate n&3, weight row grow = (n&3)*HH + u_r.
    // k-map: k = ki*32 + q*8 + e (same bijection as B layout -> sums correct).
    const int  u_r   = w * 4 + (n >> 2);
    const bool rowok = (u_r < HH);
    const int  grow  = (n & 3) * HH + (rowok ? u_r : 0);
    const float srow = ((n & 3) == 2) ? (2.0f * L2E) : (-L2E);

    f16x8 wf[5];
    #pragma unroll
    for (int ki = 0; ki < 5; ++ki) {
        #pragma unroll
        for (int e = 0; e < 8; ++e) {
            int k = ki * 32 + q * 8 + e;
            float v = 0.0f;
            if (rowok) {
                if      (k < HH)           v = W_hh0[grow * HH + k];
                else if (k < 2 * HH)       v = W_ih1[grow * HH + (k - HH)];
                else if (k < 3 * HH)       v = W_hh1[grow * HH + (k - 2 * HH)];
            }
            wf[ki][e] = (_Float16)(srow * v);
        }
    }

    // ---- chain identity: lane n<8 = L0 batch n; n>=8 = L1 batch n-8 ----
    const bool isL1 = (n >= 8);
    const int  u    = 4 * w + q;
    const int  cb   = n & 7;
    const bool wr   = (u < HH);
    const int  uc   = wr ? u : 0;

    float bz[4], wz[4];
    #pragma unroll
    for (int e = 0; e < 4; ++e) {
        int gr = e * HH + uc;
        float sc = (e == 2) ? (2.0f * L2E) : (-L2E);
        bz[e] = sc * (isL1 ? (b_ih1[gr] + b_hh1[gr]) : (b_ih0[gr] + b_hh0[gr]));
        wz[e] = isL1 ? 0.0f : (sc * W_ih0[gr]);
    }

    // ---- LDS read pointers with zero-broadcast substitution ----
    // Structural-zero fragments per strip (audited vs layout):
    //  b0: hi lanes Z            b1: lo-q3, hi-q0, hi-q1 Z
    //  b2: lo Z                  b3: lo Z
    //  b4: lo Z, hi-q3 Z
    const bool lo = (n < 8);
    const _Float16* zp = &zblk[0];
    const _Float16* p0A; const _Float16* p1A; const _Float16* p2A;
    const _Float16* p3A; const _Float16* p4A;
    const _Float16* p0B; const _Float16* p1B; const _Float16* p2B;
    const _Float16* p3B; const _Float16* p4B;
    {
        const int fo = q * 128 + n * 8;
        p0A = lo ? &shh[0][fo]            : zp;
        p0B = lo ? &shh[1][fo]            : zp;
        bool z1 = lo ? (q == 3) : (q < 2);
        p1A = z1 ? zp : &shh[0][512 + fo];
        p1B = z1 ? zp : &shh[1][512 + fo];
        p2A = lo ? zp : &shh[0][1024 + fo];
        p2B = lo ? zp : &shh[1][1024 + fo];
        p3A = lo ? zp : &shh[0][1536 + fo];
        p3B = lo ? zp : &shh[1][1536 + fo];
        bool z4 = lo || (q == 3);
        p4A = z4 ? zp : &shh[0][2048 + fo];
        p4B = z4 ? zp : &shh[1][2048 + fo];
    }

    // write offsets (same as R10)
    auto offrc = [](int r, int c) {
        return (r >> 5) * 512 + ((r >> 3) & 3) * 128 + c * 8 + (r & 7);
    };
    const int oa = isL1 ? offrc(100 + uc, cb + 8) : offrc(uc, cb);
    const int ob = offrc(50 + uc, cb + 8);
    _Float16* wpa0 = &shh[1][oa];   // step P=0 writes buf 1
    _Float16* wpa1 = &shh[0][oa];
    _Float16* wpb0 = &shh[1][ob];
    _Float16* wpb1 = &shh[0][ob];

    const float* xq = &sh_x[cb][0];
    float cst = 0.0f;

    __syncthreads();

#define MFMA(A, B, C) __builtin_amdgcn_mfma_f32_16x16x32_f16((A), (B), (C), 0, 0, 0)

#define STEP(P, T0, XI)                                                           \
    {                                                                             \
        float xi = (XI);                                                          \
        f32x4 cin;                                                                \
        cin[0] = __builtin_fmaf(xi, wz[0], bz[0]);                                \
        cin[1] = __builtin_fmaf(xi, wz[1], bz[1]);                                \
        cin[2] = __builtin_fmaf(xi, wz[2], bz[2]);                                \
        cin[3] = __builtin_fmaf(xi, wz[3], bz[3]);                                \
        f16x8 b0 = *(const f16x8*)((P) ? p0B : p0A);                              \
        f16x8 b1 = *(const f16x8*)((P) ? p1B : p1A);                              \
        f16x8 b2 = *(const f16x8*)((P) ? p2B : p2A);                              \
        f16x8 b3 = *(const f16x8*)((P) ? p3B : p3A);                              \
        f16x8 b4 = *(const f16x8*)((P) ? p4B : p4A);                              \
        f32x4 a = MFMA(wf[0], b0, cin);                                           \
        a = MFMA(wf[1], b1, a);                                                   \
        a = MFMA(wf[2], b2, a);                                                   \
        a = MFMA(wf[3], b3, a);                                                   \
        a = MFMA(wf[4], b4, a);                                                   \
        float eI = ex2_f(a[0]), eF = ex2_f(a[1]), tG = ex2_f(a[2]), eO = ex2_f(a[3]); \
        float dI = 1.0f + eI, dF = 1.0f + eF, dO = 1.0f + eO;                     \
        float IG = (tG - 1.0f) * rcp_f(dI * (tG + 1.0f));                         \
        float cn = __builtin_fmaf(rcp_f(dF), cst, IG);                            \
        cst = ((T0) && isL1) ? 0.0f : cn;                                         \
        float cc = __builtin_amdgcn_fmed3f(cst, -16.0f, 16.0f);                   \
        float tc = ex2_f(cc * (2.0f * L2E));                                      \
        float hv = (tc - 1.0f) * rcp_f(dO * (tc + 1.0f));                         \
        if (wr && !((T0) && isL1)) {                                              \
            _Float16 h16 = (_Float16)hv;                                          \
            *((P) ? wpa1 : wpa0) = h16;                                           \
            if (!isL1) *((P) ? wpb1 : wpb0) = h16;                                \
        }                                                                         \
        __syncthreads();                                                          \
    }

    // t=0 (P=0): L1 chain suppressed (h1(-1) stays 0)
    STEP(0, 1, xq[0])
    // t=1..510: 255 (odd,even) pairs
    for (int k2 = 0; k2 < 255; ++k2) {
        STEP(1, 0, xq[1])
        STEP(0, 0, xq[2])
        xq += 2;
    }
    // t=511 (P=1): writes h0(511), h1(510) into buf 0
    STEP(1, 0, xq[1])
#undef STEP

    // ---- tail: h1(511) from buf 0 (h0(511) rows 0-99, h1(510) rows 100-149) ----
    {
        f32x4 cin = {bz[0], bz[1], bz[2], bz[3]};
        f16x8 b0 = *(const f16x8*)p0A;
        f16x8 b1 = *(const f16x8*)p1A;
        f16x8 b2 = *(const f16x8*)p2A;
        f16x8 b3 = *(const f16x8*)p3A;
        f16x8 b4 = *(const f16x8*)p4A;
        f32x4 a = MFMA(wf[0], b0, cin);
        a = MFMA(wf[1], b1, a);
        a = MFMA(wf[2], b2, a);
        a = MFMA(wf[3], b3, a);
        a = MFMA(wf[4], b4, a);
        if (isL1 && wr) {
            float eI = ex2_f(a[0]), eF = ex2_f(a[1]), tG = ex2_f(a[2]), eO = ex2_f(a[3]);
            float dI = 1.0f + eI, dF = 1.0f + eF, dO = 1.0f + eO;
            float IG = (tG - 1.0f) * rcp_f(dI * (tG + 1.0f));
            float cn = __builtin_fmaf(rcp_f(dF), cst, IG);
            float cc = __builtin_amdgcn_fmed3f(cn, -16.0f, 16.0f);
            float tc = ex2_f(cc * (2.0f * L2E));
            shf[cb][uc] = (tc - 1.0f) * rcp_f(dO * (tc + 1.0f));
        }
    }
    __syncthreads();

    if (tid < MB) {
        float s = b_fc[0];
        for (int j = 0; j < HH; ++j) s += shf[tid][j] * sh_wfc[j];
        out[b0 + tid] = s;
    }
#undef MFMA
}

extern "C" void kernel_launch(void* const* d_in, const int* in_sizes, int n_in,
                              void* d_out, int out_size, void* d_ws, size_t ws_size,
                              hipStream_t stream) {
    const float* xin   = (const float*)d_in[0];
    const float* W_ih0 = (const float*)d_in[1];
    const float* W_hh0 = (const float*)d_in[2];
    const float* b_ih0 = (const float*)d_in[3];
    const float* b_hh0 = (const float*)d_in[4];
    const float* W_ih1 = (const float*)d_in[5];
    const float* W_hh1 = (const float*)d_in[6];
    const float* b_ih1 = (const float*)d_in[7];
    const float* b_hh1 = (const float*)d_in[8];
    const float* W_fc  = (const float*)d_in[9];
    const float* b_fc  = (const float*)d_in[10];
    float* out = (float*)d_out;

    lstm2_kernel<<<dim3(2048 / MB), dim3(NTHR), 0, stream>>>(
        xin, W_ih0, W_hh0, b_ih0, b_hh0, W_ih1, W_hh1, b_ih1, b_hh1, W_fc, b_fc, out);
}